// Round 1
// baseline (3494.611 us; speedup 1.0000x reference)
//
#include <hip/hip_runtime.h>

// Int4Linear: out[M,N] = x[M,K] @ dequant(W)[N,K]^T + bias[N]
// M=8192, N=11008, K=4096, W packed 2 nibbles/int32-byte (high=even k, low=odd k),
// per-row per-128-group scale/zero: w_fp = (w - z)*s.
//
// Fused dequant + bf16 MFMA GEMM. 128x128 tile, BK=32, 256 thr (4 waves 2x2),
// mfma_f32_16x16x32_bf16, LDS stride 40 (pad 8: 80B rows, 16B aligned, ~2-way
// bank aliasing which is free on gfx950).

#define M_TOTAL 8192
#define N_TOTAL 11008
#define K_TOTAL 4096
#define KP      2048      // packed int32 per W row
#define NG      32        // quant groups per row
#define BM      128
#define BN      128
#define BK      32
#define LDS_STRIDE 40     // BK + 8 pad (elements)
#define MTILES  (M_TOTAL / BM)   // 64
#define NTILES  (N_TOTAL / BN)   // 86

typedef __bf16 bf16x8 __attribute__((ext_vector_type(8)));
typedef float  f32x4  __attribute__((ext_vector_type(4)));

__device__ __forceinline__ unsigned pack2_bf16(float f0, float f1) {
    // f0 -> low 16 (element k), f1 -> high 16 (element k+1); round-half-up
    unsigned b0 = __float_as_uint(f0);
    unsigned b1 = __float_as_uint(f1);
    return ((b0 + 0x8000u) >> 16) | ((b1 + 0x8000u) & 0xFFFF0000u);
}

__global__ __launch_bounds__(256)
void int4linear_fused(const float* __restrict__ x,
                      const int*   __restrict__ wp,
                      const float* __restrict__ scale,
                      const float* __restrict__ zp,
                      const float* __restrict__ bias,
                      float*       __restrict__ out)
{
    __shared__ unsigned short As[BM * LDS_STRIDE];
    __shared__ unsigned short Bs[BN * LDS_STRIDE];

    const int t = threadIdx.x;

    // block swizzle: groups of 8 m-tiles, n inner -> A panel reuse in L2/LLC
    int bid = blockIdx.x;
    const int per_group = 8 * NTILES;
    int grp = bid / per_group;
    int ing = bid - grp * per_group;
    int m_tile = grp * 8 + (ing & 7);
    int n_tile = ing >> 3;

    const int m0 = m_tile * BM;
    const int n0 = n_tile * BN;

    // ---- staging mapping: 2 threads per row, each does 16 k-elements ----
    const int srow  = t >> 1;   // 0..127
    const int shalf = t & 1;    // 0..1

    const float* aptr = x  + (size_t)(m0 + srow) * K_TOTAL + shalf * 16;
    const int*   bptr = wp + (size_t)(n0 + srow) * KP      + shalf * 8;
    const float* sptr = scale + (size_t)(n0 + srow) * NG;
    const float* zptr = zp    + (size_t)(n0 + srow) * NG;

    unsigned short* AsW = &As[srow * LDS_STRIDE + shalf * 16];
    unsigned short* BsW = &Bs[srow * LDS_STRIDE + shalf * 16];

    // ---- wave / fragment mapping ----
    const int wave = t >> 6;
    const int lane = t & 63;
    const int wm   = wave >> 1;   // 0..1
    const int wn   = wave & 1;    // 0..1
    const int quad = lane >> 4;   // 0..3
    const int l15  = lane & 15;

    const unsigned short* AsR = &As[(wm * 64 + l15) * LDS_STRIDE + quad * 8];
    const unsigned short* BsR = &Bs[(wn * 64 + l15) * LDS_STRIDE + quad * 8];

    f32x4 acc[4][4];
    #pragma unroll
    for (int i = 0; i < 4; ++i)
        #pragma unroll
        for (int j = 0; j < 4; ++j)
            acc[i][j] = (f32x4){0.f, 0.f, 0.f, 0.f};

    for (int kt = 0; kt < K_TOTAL / BK; ++kt) {
        // ---- global loads (issued before barrier for latency hiding) ----
        float4 a0 = ((const float4*)aptr)[0];
        float4 a1 = ((const float4*)aptr)[1];
        float4 a2 = ((const float4*)aptr)[2];
        float4 a3 = ((const float4*)aptr)[3];
        int4   b0 = ((const int4*)bptr)[0];
        int4   b1 = ((const int4*)bptr)[1];
        const int g = kt >> 2;              // 4 K-tiles per quant group
        float s = sptr[g];
        float c = -zptr[g] * s;             // (w - z)*s = w*s + c
        aptr += BK;
        bptr += BK / 2;

        __syncthreads();   // previous iter's LDS reads done before overwrite

        // ---- A: fp32 -> bf16 pack -> LDS ----
        unsigned au0 = pack2_bf16(a0.x, a0.y), au1 = pack2_bf16(a0.z, a0.w);
        unsigned au2 = pack2_bf16(a1.x, a1.y), au3 = pack2_bf16(a1.z, a1.w);
        unsigned au4 = pack2_bf16(a2.x, a2.y), au5 = pack2_bf16(a2.z, a2.w);
        unsigned au6 = pack2_bf16(a3.x, a3.y), au7 = pack2_bf16(a3.z, a3.w);
        ((uint4*)AsW)[0] = make_uint4(au0, au1, au2, au3);
        ((uint4*)AsW)[1] = make_uint4(au4, au5, au6, au7);

        // ---- B: nibble dequant -> bf16 pack -> LDS ----
        int bv[8] = {b0.x, b0.y, b0.z, b0.w, b1.x, b1.y, b1.z, b1.w};
        unsigned bu[8];
        #pragma unroll
        for (int j = 0; j < 8; ++j) {
            unsigned v = (unsigned)bv[j];
            float fh = (float)((v >> 4) & 15u) * s + c;  // even k: high nibble
            float fl = (float)( v       & 15u) * s + c;  // odd  k: low nibble
            bu[j] = pack2_bf16(fh, fl);
        }
        ((uint4*)BsW)[0] = make_uint4(bu[0], bu[1], bu[2], bu[3]);
        ((uint4*)BsW)[1] = make_uint4(bu[4], bu[5], bu[6], bu[7]);

        __syncthreads();

        // ---- fragments + MFMA ----
        bf16x8 af[4], bf[4];
        #pragma unroll
        for (int i = 0; i < 4; ++i) {
            af[i] = *(const bf16x8*)(AsR + i * 16 * LDS_STRIDE);
            bf[i] = *(const bf16x8*)(BsR + i * 16 * LDS_STRIDE);
        }
        #pragma unroll
        for (int i = 0; i < 4; ++i)
            #pragma unroll
            for (int j = 0; j < 4; ++j)
                acc[i][j] = __builtin_amdgcn_mfma_f32_16x16x32_bf16(
                    af[i], bf[j], acc[i][j], 0, 0, 0);
    }

    // ---- epilogue: C/D layout col=lane&15, row=quad*4+reg ----
    const int m_base = m0 + wm * 64;
    const int n_base = n0 + wn * 64;

    float bvec[4];
    #pragma unroll
    for (int j = 0; j < 4; ++j) bvec[j] = bias[n_base + j * 16 + l15];

    #pragma unroll
    for (int i = 0; i < 4; ++i) {
        #pragma unroll
        for (int j = 0; j < 4; ++j) {
            const int col = n_base + j * 16 + l15;
            #pragma unroll
            for (int r = 0; r < 4; ++r) {
                const int row = m_base + i * 16 + quad * 4 + r;
                out[(size_t)row * N_TOTAL + col] = acc[i][j][r] + bvec[j];
            }
        }
    }
}

extern "C" void kernel_launch(void* const* d_in, const int* in_sizes, int n_in,
                              void* d_out, int out_size, void* d_ws, size_t ws_size,
                              hipStream_t stream) {
    const float* x     = (const float*)d_in[0];
    const int*   wpk   = (const int*)  d_in[1];
    const float* scale = (const float*)d_in[2];
    const float* zp    = (const float*)d_in[3];
    const float* bias  = (const float*)d_in[4];
    float* out = (float*)d_out;

    dim3 grid(MTILES * NTILES);   // 64*86 = 5504
    int4linear_fused<<<grid, 256, 0, stream>>>(x, wpk, scale, zp, bias, out);
}

// Round 2
// 1402.114 us; speedup vs baseline: 2.4924x; 2.4924x over previous
//
#include <hip/hip_runtime.h>
#include <stdint.h>

// Int4Linear: out[M,N] = x[M,K] @ dequant(W)[N,K]^T + bias[N]
// M=8192, N=11008, K=4096.
//
// R2: two-pass. Pass 1 converts x->bf16 and dequants W->bf16 into d_ws
// (157.3 MB; falls back to R1 fused kernel if ws too small). Pass 2 is the
// m97-structure bf16 GEMM: 128x128 tile, BK=32, global_load_lds width=16
// into unpadded LDS, 2-barrier K-loop, mfma_f32_16x16x32_bf16, 4x4 acc/wave.

#define M_TOTAL 8192
#define N_TOTAL 11008
#define K_TOTAL 4096
#define KP      2048
#define NG      32
#define BM      128
#define BN      128
#define BK      32
#define MT      (M_TOTAL / BM)   // 64
#define NT      (N_TOTAL / BN)   // 86

typedef __bf16 bf16x8 __attribute__((ext_vector_type(8)));
typedef float  f32x4  __attribute__((ext_vector_type(4)));

__device__ __forceinline__ unsigned pack2_bf16(float f0, float f1) {
    // f0 -> low 16 (even k), f1 -> high 16 (odd k); round-half-up
    unsigned b0 = __float_as_uint(f0);
    unsigned b1 = __float_as_uint(f1);
    return ((b0 + 0x8000u) >> 16) | ((b1 + 0x8000u) & 0xFFFF0000u);
}

// ---------------- pass 1a: x fp32 -> bf16 ----------------
__global__ __launch_bounds__(256)
void convert_x(const float* __restrict__ x, unsigned short* __restrict__ xb)
{
    size_t i = ((size_t)blockIdx.x * 256 + threadIdx.x) * 8;
    float4 a0 = *(const float4*)(x + i);
    float4 a1 = *(const float4*)(x + i + 4);
    uint4 o;
    o.x = pack2_bf16(a0.x, a0.y);
    o.y = pack2_bf16(a0.z, a0.w);
    o.z = pack2_bf16(a1.x, a1.y);
    o.w = pack2_bf16(a1.z, a1.w);
    *(uint4*)(xb + i) = o;
}

// ---------------- pass 1b: W int4 -> bf16 [N,K] row-major ----------------
__global__ __launch_bounds__(256)
void dequant_w(const int* __restrict__ wp, const float* __restrict__ scale,
               const float* __restrict__ zp, unsigned short* __restrict__ wb)
{
    size_t tid = (size_t)blockIdx.x * 256 + threadIdx.x;
    size_t pi = tid * 4;                       // packed-int index
    int row = (int)(pi >> 11);                 // / KP
    int p0  = (int)(pi & (KP - 1));
    int g   = p0 >> 6;                         // 64 packed ints per 128-group
    float s = scale[row * NG + g];
    float c = -zp[row * NG + g] * s;           // (w - z)*s = w*s + c
    int4 v = *(const int4*)(wp + pi);
    int bv[4] = {v.x, v.y, v.z, v.w};
    unsigned ou[4];
    #pragma unroll
    for (int j = 0; j < 4; ++j) {
        unsigned u = (unsigned)bv[j];
        float fh = (float)((u >> 4) & 15u) * s + c;  // even k: high nibble
        float fl = (float)( u       & 15u) * s + c;  // odd  k: low nibble
        ou[j] = pack2_bf16(fh, fl);
    }
    *(uint4*)(wb + 2 * pi) = make_uint4(ou[0], ou[1], ou[2], ou[3]);
}

// ---------------- pass 2: m97-structure bf16 GEMM ----------------
__device__ __forceinline__ void load_lds16(const void* g, void* l) {
    __builtin_amdgcn_global_load_lds(
        (const __attribute__((address_space(1))) unsigned int*)(uintptr_t)g,
        (__attribute__((address_space(3))) unsigned int*)(uintptr_t)l,
        16, 0, 0);
}

__global__ __launch_bounds__(256)
void gemm_bt(const unsigned short* __restrict__ A,   // [M,K] bf16
             const unsigned short* __restrict__ B,   // [N,K] bf16
             const float* __restrict__ bias,
             float* __restrict__ out)
{
    __shared__ unsigned short As[BM * BK];   // 8 KB, unpadded (global_load_lds)
    __shared__ unsigned short Bs[BN * BK];   // 8 KB

    const int t = threadIdx.x;
    const int wave = t >> 6, lane = t & 63;

    // group-of-8 m-tiles swizzle (L2/LLC reuse of A panels)
    int bid = blockIdx.x;
    const int per_group = 8 * NT;
    int grp = bid / per_group;
    int ing = bid - grp * per_group;
    int m0 = (grp * 8 + (ing & 7)) * BM;
    int n0 = (ing >> 3) * BN;

    // staging: chunk c (0..7) covers tile rows c*16..c*16+15; lane -> (row, col)
    const int c0   = wave * 2;
    const int lrow = lane >> 2;          // 0..15
    const int lcol = (lane & 3) * 8;     // 0,8,16,24
    const unsigned short* gA0 = A + (size_t)(m0 + c0 * 16 + lrow) * K_TOTAL + lcol;
    const unsigned short* gA1 = gA0 + 16 * K_TOTAL;
    const unsigned short* gB0 = B + (size_t)(n0 + c0 * 16 + lrow) * K_TOTAL + lcol;
    const unsigned short* gB1 = gB0 + 16 * K_TOTAL;
    unsigned short* lA0 = &As[c0 * 512];        // wave-uniform LDS bases
    unsigned short* lA1 = &As[c0 * 512 + 512];
    unsigned short* lB0 = &Bs[c0 * 512];
    unsigned short* lB1 = &Bs[c0 * 512 + 512];

    // fragment mapping (2x2 waves, each 64x64 = 4x4 MFMA 16x16 tiles)
    const int wm = wave >> 1, wn = wave & 1;
    const int quad = lane >> 4, l15 = lane & 15;
    const unsigned short* AsR = &As[(wm * 64 + l15) * BK + quad * 8];
    const unsigned short* BsR = &Bs[(wn * 64 + l15) * BK + quad * 8];

    f32x4 acc[4][4];
    #pragma unroll
    for (int i = 0; i < 4; ++i)
        #pragma unroll
        for (int j = 0; j < 4; ++j)
            acc[i][j] = (f32x4){0.f, 0.f, 0.f, 0.f};

    for (int kt = 0; kt < K_TOTAL / BK; ++kt) {
        load_lds16(gA0, lA0);
        load_lds16(gA1, lA1);
        load_lds16(gB0, lB0);
        load_lds16(gB1, lB1);
        gA0 += BK; gA1 += BK; gB0 += BK; gB1 += BK;

        __syncthreads();   // drains vmcnt -> LDS tiles ready

        bf16x8 af[4], bf[4];
        #pragma unroll
        for (int i = 0; i < 4; ++i) {
            af[i] = *(const bf16x8*)(AsR + i * 16 * BK);
            bf[i] = *(const bf16x8*)(BsR + i * 16 * BK);
        }
        #pragma unroll
        for (int i = 0; i < 4; ++i)
            #pragma unroll
            for (int j = 0; j < 4; ++j)
                acc[i][j] = __builtin_amdgcn_mfma_f32_16x16x32_bf16(
                    af[i], bf[j], acc[i][j], 0, 0, 0);

        __syncthreads();   // reads done before next iter overwrites
    }

    // epilogue: C/D layout col=lane&15, row=quad*4+reg
    const int m_base = m0 + wm * 64;
    const int n_base = n0 + wn * 64;

    float bvec[4];
    #pragma unroll
    for (int j = 0; j < 4; ++j) bvec[j] = bias[n_base + j * 16 + l15];

    #pragma unroll
    for (int i = 0; i < 4; ++i) {
        #pragma unroll
        for (int j = 0; j < 4; ++j) {
            const int col = n_base + j * 16 + l15;
            #pragma unroll
            for (int r = 0; r < 4; ++r) {
                const int row = m_base + i * 16 + quad * 4 + r;
                out[(size_t)row * N_TOTAL + col] = acc[i][j][r] + bvec[j];
            }
        }
    }
}

// ---------------- R1 fused kernel (fallback if ws too small) ----------------
#define LDS_STRIDE 40

__global__ __launch_bounds__(256)
void int4linear_fused(const float* __restrict__ x,
                      const int*   __restrict__ wp,
                      const float* __restrict__ scale,
                      const float* __restrict__ zp,
                      const float* __restrict__ bias,
                      float*       __restrict__ out)
{
    __shared__ unsigned short As[BM * LDS_STRIDE];
    __shared__ unsigned short Bs[BN * LDS_STRIDE];

    const int t = threadIdx.x;
    int bid = blockIdx.x;
    const int per_group = 8 * NT;
    int grp = bid / per_group;
    int ing = bid - grp * per_group;
    int m0 = (grp * 8 + (ing & 7)) * BM;
    int n0 = (ing >> 3) * BN;

    const int srow  = t >> 1;
    const int shalf = t & 1;

    const float* aptr = x  + (size_t)(m0 + srow) * K_TOTAL + shalf * 16;
    const int*   bptr = wp + (size_t)(n0 + srow) * KP      + shalf * 8;
    const float* sptr = scale + (size_t)(n0 + srow) * NG;
    const float* zptr = zp    + (size_t)(n0 + srow) * NG;

    unsigned short* AsW = &As[srow * LDS_STRIDE + shalf * 16];
    unsigned short* BsW = &Bs[srow * LDS_STRIDE + shalf * 16];

    const int wave = t >> 6;
    const int lane = t & 63;
    const int wm   = wave >> 1;
    const int wn   = wave & 1;
    const int quad = lane >> 4;
    const int l15  = lane & 15;

    const unsigned short* AsR = &As[(wm * 64 + l15) * LDS_STRIDE + quad * 8];
    const unsigned short* BsR = &Bs[(wn * 64 + l15) * LDS_STRIDE + quad * 8];

    f32x4 acc[4][4];
    #pragma unroll
    for (int i = 0; i < 4; ++i)
        #pragma unroll
        for (int j = 0; j < 4; ++j)
            acc[i][j] = (f32x4){0.f, 0.f, 0.f, 0.f};

    for (int kt = 0; kt < K_TOTAL / BK; ++kt) {
        float4 a0 = ((const float4*)aptr)[0];
        float4 a1 = ((const float4*)aptr)[1];
        float4 a2 = ((const float4*)aptr)[2];
        float4 a3 = ((const float4*)aptr)[3];
        int4   b0 = ((const int4*)bptr)[0];
        int4   b1 = ((const int4*)bptr)[1];
        const int g = kt >> 2;
        float s = sptr[g];
        float c = -zptr[g] * s;
        aptr += BK;
        bptr += BK / 2;

        __syncthreads();

        unsigned au0 = pack2_bf16(a0.x, a0.y), au1 = pack2_bf16(a0.z, a0.w);
        unsigned au2 = pack2_bf16(a1.x, a1.y), au3 = pack2_bf16(a1.z, a1.w);
        unsigned au4 = pack2_bf16(a2.x, a2.y), au5 = pack2_bf16(a2.z, a2.w);
        unsigned au6 = pack2_bf16(a3.x, a3.y), au7 = pack2_bf16(a3.z, a3.w);
        ((uint4*)AsW)[0] = make_uint4(au0, au1, au2, au3);
        ((uint4*)AsW)[1] = make_uint4(au4, au5, au6, au7);

        int bv[8] = {b0.x, b0.y, b0.z, b0.w, b1.x, b1.y, b1.z, b1.w};
        unsigned bu[8];
        #pragma unroll
        for (int j = 0; j < 8; ++j) {
            unsigned v = (unsigned)bv[j];
            float fh = (float)((v >> 4) & 15u) * s + c;
            float fl = (float)( v       & 15u) * s + c;
            bu[j] = pack2_bf16(fh, fl);
        }
        ((uint4*)BsW)[0] = make_uint4(bu[0], bu[1], bu[2], bu[3]);
        ((uint4*)BsW)[1] = make_uint4(bu[4], bu[5], bu[6], bu[7]);

        __syncthreads();

        bf16x8 af[4], bf[4];
        #pragma unroll
        for (int i = 0; i < 4; ++i) {
            af[i] = *(const bf16x8*)(AsR + i * 16 * LDS_STRIDE);
            bf[i] = *(const bf16x8*)(BsR + i * 16 * LDS_STRIDE);
        }
        #pragma unroll
        for (int i = 0; i < 4; ++i)
            #pragma unroll
            for (int j = 0; j < 4; ++j)
                acc[i][j] = __builtin_amdgcn_mfma_f32_16x16x32_bf16(
                    af[i], bf[j], acc[i][j], 0, 0, 0);
    }

    const int m_base = m0 + wm * 64;
    const int n_base = n0 + wn * 64;

    float bvec[4];
    #pragma unroll
    for (int j = 0; j < 4; ++j) bvec[j] = bias[n_base + j * 16 + l15];

    #pragma unroll
    for (int i = 0; i < 4; ++i) {
        #pragma unroll
        for (int j = 0; j < 4; ++j) {
            const int col = n_base + j * 16 + l15;
            #pragma unroll
            for (int r = 0; r < 4; ++r) {
                const int row = m_base + i * 16 + quad * 4 + r;
                out[(size_t)row * N_TOTAL + col] = acc[i][j][r] + bvec[j];
            }
        }
    }
}

extern "C" void kernel_launch(void* const* d_in, const int* in_sizes, int n_in,
                              void* d_out, int out_size, void* d_ws, size_t ws_size,
                              hipStream_t stream) {
    const float* x     = (const float*)d_in[0];
    const int*   wpk   = (const int*)  d_in[1];
    const float* scale = (const float*)d_in[2];
    const float* zp    = (const float*)d_in[3];
    const float* bias  = (const float*)d_in[4];
    float* out = (float*)d_out;

    const size_t xb_elems = (size_t)M_TOTAL * K_TOTAL;            // 33.5M
    const size_t wb_elems = (size_t)N_TOTAL * K_TOTAL;            // 45.1M
    const size_t need = (xb_elems + wb_elems) * sizeof(unsigned short); // 157.3 MB

    if (ws_size >= need) {
        unsigned short* xb = (unsigned short*)d_ws;
        unsigned short* wb = xb + xb_elems;

        convert_x<<<dim3((unsigned)(xb_elems / (256 * 8))), 256, 0, stream>>>(x, xb);
        dequant_w<<<dim3((unsigned)((size_t)N_TOTAL * KP / (256 * 4))), 256, 0, stream>>>(
            wpk, scale, zp, wb);
        gemm_bt<<<dim3(MT * NT), 256, 0, stream>>>(xb, wb, bias, out);
    } else {
        int4linear_fused<<<dim3(MT * NT), 256, 0, stream>>>(x, wpk, scale, zp, bias, out);
    }
}